// Round 4
// baseline (236.595 us; speedup 1.0000x reference)
//
#include <hip/hip_runtime.h>

#define CPB 128
#define BLOCK 256
#define NCELLS (4096 * 14 * 14)
#define NBLOCKS (NCELLS / CPB)        // 6272, exact
#define NF (CPB * 30)                 // 3840 floats per input per block
#define NF4 (NF / 4)                  // 960 float4 per input per block
#define TOT4 (2 * NF4)                // 1920
#define TAIL (TOT4 - 7 * BLOCK)       // 128

__global__ __launch_bounds__(BLOCK) void yolo_fused(
    const float* __restrict__ pred,
    const float* __restrict__ targ,
    float* __restrict__ partial,
    unsigned int* __restrict__ counter,
    float* __restrict__ out)
{
    __shared__ float lds[2 * NF];          // 30720 B, linear layout, no pad
    __shared__ float wsum[BLOCK / 64];
    __shared__ unsigned int last_flag;

    const int tid = threadIdx.x;
    const int bid = blockIdx.x;
    const size_t gbase = (size_t)bid * NF;
    const float4* pp4 = reinterpret_cast<const float4*>(pred + gbase);
    const float4* tp4 = reinterpret_cast<const float4*>(targ + gbase);
    float4* lds4 = reinterpret_cast<float4*>(lds);

    // ---- staging: pure linear float4 copy, loads first (MLP), then LDS writes
    float4 r0, r1, r2, r3, r4, r5, r6, r7;
    {
        // k*BLOCK boundaries align with wave boundaries and with NF4=960,
        // so every wave's predicate below is uniform.
        int i0 = tid;              r0 = (i0 < NF4) ? pp4[i0] : tp4[i0 - NF4];
        int i1 = tid + 1 * BLOCK;  r1 = (i1 < NF4) ? pp4[i1] : tp4[i1 - NF4];
        int i2 = tid + 2 * BLOCK;  r2 = (i2 < NF4) ? pp4[i2] : tp4[i2 - NF4];
        int i3 = tid + 3 * BLOCK;  r3 = (i3 < NF4) ? pp4[i3] : tp4[i3 - NF4];
        int i4 = tid + 4 * BLOCK;  r4 = (i4 < NF4) ? pp4[i4] : tp4[i4 - NF4];
        int i5 = tid + 5 * BLOCK;  r5 = (i5 < NF4) ? pp4[i5] : tp4[i5 - NF4];
        int i6 = tid + 6 * BLOCK;  r6 = (i6 < NF4) ? pp4[i6] : tp4[i6 - NF4];
        if (tid < TAIL) { int i7 = tid + 7 * BLOCK; r7 = tp4[i7 - NF4]; }
    }
    lds4[tid]             = r0;
    lds4[tid + 1 * BLOCK] = r1;
    lds4[tid + 2 * BLOCK] = r2;
    lds4[tid + 3 * BLOCK] = r3;
    lds4[tid + 4 * BLOCK] = r4;
    lds4[tid + 5 * BLOCK] = r5;
    lds4[tid + 6 * BLOCK] = r6;
    if (tid < TAIL) lds4[tid + 7 * BLOCK] = r7;
    __syncthreads();

    // ---- compute: waves 0-1 box math for cell=tid; waves 2-3 class loss
    float loss = 0.0f;
    if (tid < CPB) {
        const float* pc = &lds[tid * 30];
        const float* tc = &lds[NF + tid * 30];

        float pv0 = pc[0], pv1 = pc[1], pv2 = pc[2], pv3 = pc[3], pv4 = pc[4];
        float pv5 = pc[5], pv6 = pc[6], pv7 = pc[7], pv8 = pc[8], pv9 = pc[9];
        float tv0 = tc[0], tv1 = tc[1], tv2 = tc[2], tv3 = tc[3], tv4 = tc[4];
        float tv5 = tc[5], tv6 = tc[6], tv7 = tc[7], tv8 = tc[8];

        bool obj = tv4 > 0.0f;

        if (!obj) {
            float d4 = pv4 - tv4;
            float d9 = pv9 - tc[9];
            loss = 0.5f * (d4 * d4 + d9 * d9);
        } else {
            float tcx = tv0 / 14.0f, tcy = tv1 / 14.0f;
            float t_ltx = tcx - 0.5f * tv2;
            float t_lty = tcy - 0.5f * tv3;
            float t_rbx = tcx + 0.5f * tv2;
            float t_rby = tcy + 0.5f * tv3;
            float area_t = (t_rbx - t_ltx) * (t_rby - t_lty);

            float p0cx = pv0 / 14.0f, p0cy = pv1 / 14.0f;
            float p0_ltx = p0cx - 0.5f * pv2;
            float p0_lty = p0cy - 0.5f * pv3;
            float p0_rbx = p0cx + 0.5f * pv2;
            float p0_rby = p0cy + 0.5f * pv3;
            float w0x = fmaxf(fminf(p0_rbx, t_rbx) - fmaxf(p0_ltx, t_ltx), 0.0f);
            float w0y = fmaxf(fminf(p0_rby, t_rby) - fmaxf(p0_lty, t_lty), 0.0f);
            float inter0 = w0x * w0y;
            float area_p0 = (p0_rbx - p0_ltx) * (p0_rby - p0_lty);
            float iou0 = inter0 / (area_p0 + area_t - inter0);

            float p1cx = pv5 / 14.0f, p1cy = pv6 / 14.0f;
            float p1_ltx = p1cx - 0.5f * pv7;
            float p1_lty = p1cy - 0.5f * pv8;
            float p1_rbx = p1cx + 0.5f * pv7;
            float p1_rby = p1cy + 0.5f * pv8;
            float w1x = fmaxf(fminf(p1_rbx, t_rbx) - fmaxf(p1_ltx, t_ltx), 0.0f);
            float w1y = fmaxf(fminf(p1_rby, t_rby) - fmaxf(p1_lty, t_lty), 0.0f);
            float inter1 = w1x * w1y;
            float area_p1 = (p1_rbx - p1_ltx) * (p1_rby - p1_lty);
            float iou1 = inter1 / (area_p1 + area_t - inter1);

            bool best1 = iou1 > iou0;          // tie -> box 0
            float max_iou = fmaxf(iou0, iou1);

            float pbr0 = best1 ? pv5 : pv0;
            float pbr1 = best1 ? pv6 : pv1;
            float pbr2 = best1 ? pv7 : pv2;
            float pbr3 = best1 ? pv8 : pv3;
            float pbr4 = best1 ? pv9 : pv4;
            float tbr0 = best1 ? tv5 : tv0;
            float tbr1 = best1 ? tv6 : tv1;
            float tbr2 = best1 ? tv7 : tv2;
            float tbr3 = best1 ? tv8 : tv3;

            float dcf = pbr4 - max_iou;
            float contain = dcf * dcf;

            float dx = pbr0 - tbr0;
            float dy = pbr1 - tbr1;
            float reg_xy = dx * dx + dy * dy;

            float dw = sqrtf(pbr2) - sqrtf(tbr2);
            float dh = sqrtf(pbr3) - sqrtf(tbr3);
            float reg_wh = dw * dw + dh * dh;

            loss = contain + 5.0f * (reg_xy + reg_wh);
        }
    } else {
        int c = tid - CPB;
        const float* pc = &lds[c * 30];
        const float* tc = &lds[NF + c * 30];
        if (tc[4] > 0.0f) {
            float cls = 0.0f;
            #pragma unroll
            for (int e = 10; e < 30; ++e) {
                float d = pc[e] - tc[e];
                cls += d * d;
            }
            loss = cls;
        }
    }

    // ---- block reduction
    #pragma unroll
    for (int off = 32; off > 0; off >>= 1)
        loss += __shfl_down(loss, off, 64);

    int lane = tid & 63;
    int wid = tid >> 6;
    if (lane == 0) wsum[wid] = loss;
    __syncthreads();

    if (tid == 0) {
        partial[bid] = wsum[0] + wsum[1] + wsum[2] + wsum[3];
        __threadfence();                       // make partial visible device-wide
        unsigned int t = atomicAdd(counter, 1u);
        last_flag = (t == NBLOCKS - 1) ? 1u : 0u;
    }
    __syncthreads();

    // ---- last block: deterministic final reduction (fixed index order)
    if (last_flag) {
        __threadfence();
        float s = 0.0f;
        for (int i = tid; i < NBLOCKS; i += BLOCK)
            s += partial[i];

        #pragma unroll
        for (int off = 32; off > 0; off >>= 1)
            s += __shfl_down(s, off, 64);

        if (lane == 0) wsum[wid] = s;
        __syncthreads();
        if (tid == 0)
            out[0] = (wsum[0] + wsum[1] + wsum[2] + wsum[3]) * (1.0f / 4096.0f);
    }
}

extern "C" void kernel_launch(void* const* d_in, const int* in_sizes, int n_in,
                              void* d_out, int out_size, void* d_ws, size_t ws_size,
                              hipStream_t stream) {
    const float* pred = (const float*)d_in[0];
    const float* targ = (const float*)d_in[1];
    float* out = (float*)d_out;
    float* partial = (float*)d_ws;
    unsigned int* counter = (unsigned int*)((char*)d_ws + NBLOCKS * sizeof(float));

    // d_ws is poisoned 0xAA by the harness and never re-poisoned: zero the
    // ticket counter every call (captures as a memset node in the graph).
    hipMemsetAsync(counter, 0, sizeof(unsigned int), stream);
    yolo_fused<<<NBLOCKS, BLOCK, 0, stream>>>(pred, targ, partial, counter, out);
}

// Round 5
// 35.934 us; speedup vs baseline: 6.5841x; 6.5841x over previous
//
#include <hip/hip_runtime.h>

#define CPB 128
#define BLOCK 256
#define NCELLS (4096 * 14 * 14)
#define NBLOCKS (NCELLS / CPB)        // 6272, exact
#define NF (CPB * 30)                 // 3840 floats per input per block
#define NF4 (NF / 4)                  // 960 float4 per input per block
#define TOT4 (2 * NF4)                // 1920
#define TAIL (TOT4 - 7 * BLOCK)       // 128

__global__ __launch_bounds__(BLOCK) void yolo_partial(
    const float* __restrict__ pred,
    const float* __restrict__ targ,
    float* __restrict__ partial)
{
    __shared__ float lds[2 * NF];          // 30720 B, linear layout, no pad
    __shared__ float wsum[BLOCK / 64];

    const int tid = threadIdx.x;
    const int bid = blockIdx.x;
    const size_t gbase = (size_t)bid * NF;
    const float4* pp4 = reinterpret_cast<const float4*>(pred + gbase);
    const float4* tp4 = reinterpret_cast<const float4*>(targ + gbase);
    float4* lds4 = reinterpret_cast<float4*>(lds);

    // ---- staging: pure linear float4 copy, loads first (MLP), then LDS writes
    float4 r0, r1, r2, r3, r4, r5, r6, r7;
    {
        // k*BLOCK boundaries align with wave boundaries and with NF4=960,
        // so every wave's predicate below is uniform.
        int i0 = tid;              r0 = (i0 < NF4) ? pp4[i0] : tp4[i0 - NF4];
        int i1 = tid + 1 * BLOCK;  r1 = (i1 < NF4) ? pp4[i1] : tp4[i1 - NF4];
        int i2 = tid + 2 * BLOCK;  r2 = (i2 < NF4) ? pp4[i2] : tp4[i2 - NF4];
        int i3 = tid + 3 * BLOCK;  r3 = (i3 < NF4) ? pp4[i3] : tp4[i3 - NF4];
        int i4 = tid + 4 * BLOCK;  r4 = (i4 < NF4) ? pp4[i4] : tp4[i4 - NF4];
        int i5 = tid + 5 * BLOCK;  r5 = (i5 < NF4) ? pp4[i5] : tp4[i5 - NF4];
        int i6 = tid + 6 * BLOCK;  r6 = (i6 < NF4) ? pp4[i6] : tp4[i6 - NF4];
        if (tid < TAIL) { int i7 = tid + 7 * BLOCK; r7 = tp4[i7 - NF4]; }
    }
    lds4[tid]             = r0;
    lds4[tid + 1 * BLOCK] = r1;
    lds4[tid + 2 * BLOCK] = r2;
    lds4[tid + 3 * BLOCK] = r3;
    lds4[tid + 4 * BLOCK] = r4;
    lds4[tid + 5 * BLOCK] = r5;
    lds4[tid + 6 * BLOCK] = r6;
    if (tid < TAIL) lds4[tid + 7 * BLOCK] = r7;
    __syncthreads();

    // ---- compute: waves 0-1 box math for cell=tid; waves 2-3 class loss
    float loss = 0.0f;
    if (tid < CPB) {
        const float* pc = &lds[tid * 30];
        const float* tc = &lds[NF + tid * 30];

        float pv0 = pc[0], pv1 = pc[1], pv2 = pc[2], pv3 = pc[3], pv4 = pc[4];
        float pv5 = pc[5], pv6 = pc[6], pv7 = pc[7], pv8 = pc[8], pv9 = pc[9];
        float tv0 = tc[0], tv1 = tc[1], tv2 = tc[2], tv3 = tc[3], tv4 = tc[4];
        float tv5 = tc[5], tv6 = tc[6], tv7 = tc[7], tv8 = tc[8];

        bool obj = tv4 > 0.0f;

        if (!obj) {
            float d4 = pv4 - tv4;
            float d9 = pv9 - tc[9];
            loss = 0.5f * (d4 * d4 + d9 * d9);
        } else {
            float tcx = tv0 / 14.0f, tcy = tv1 / 14.0f;
            float t_ltx = tcx - 0.5f * tv2;
            float t_lty = tcy - 0.5f * tv3;
            float t_rbx = tcx + 0.5f * tv2;
            float t_rby = tcy + 0.5f * tv3;
            float area_t = (t_rbx - t_ltx) * (t_rby - t_lty);

            float p0cx = pv0 / 14.0f, p0cy = pv1 / 14.0f;
            float p0_ltx = p0cx - 0.5f * pv2;
            float p0_lty = p0cy - 0.5f * pv3;
            float p0_rbx = p0cx + 0.5f * pv2;
            float p0_rby = p0cy + 0.5f * pv3;
            float w0x = fmaxf(fminf(p0_rbx, t_rbx) - fmaxf(p0_ltx, t_ltx), 0.0f);
            float w0y = fmaxf(fminf(p0_rby, t_rby) - fmaxf(p0_lty, t_lty), 0.0f);
            float inter0 = w0x * w0y;
            float area_p0 = (p0_rbx - p0_ltx) * (p0_rby - p0_lty);
            float iou0 = inter0 / (area_p0 + area_t - inter0);

            float p1cx = pv5 / 14.0f, p1cy = pv6 / 14.0f;
            float p1_ltx = p1cx - 0.5f * pv7;
            float p1_lty = p1cy - 0.5f * pv8;
            float p1_rbx = p1cx + 0.5f * pv7;
            float p1_rby = p1cy + 0.5f * pv8;
            float w1x = fmaxf(fminf(p1_rbx, t_rbx) - fmaxf(p1_ltx, t_ltx), 0.0f);
            float w1y = fmaxf(fminf(p1_rby, t_rby) - fmaxf(p1_lty, t_lty), 0.0f);
            float inter1 = w1x * w1y;
            float area_p1 = (p1_rbx - p1_ltx) * (p1_rby - p1_lty);
            float iou1 = inter1 / (area_p1 + area_t - inter1);

            bool best1 = iou1 > iou0;          // tie -> box 0
            float max_iou = fmaxf(iou0, iou1);

            float pbr0 = best1 ? pv5 : pv0;
            float pbr1 = best1 ? pv6 : pv1;
            float pbr2 = best1 ? pv7 : pv2;
            float pbr3 = best1 ? pv8 : pv3;
            float pbr4 = best1 ? pv9 : pv4;
            float tbr0 = best1 ? tv5 : tv0;
            float tbr1 = best1 ? tv6 : tv1;
            float tbr2 = best1 ? tv7 : tv2;
            float tbr3 = best1 ? tv8 : tv3;

            float dcf = pbr4 - max_iou;
            float contain = dcf * dcf;

            float dx = pbr0 - tbr0;
            float dy = pbr1 - tbr1;
            float reg_xy = dx * dx + dy * dy;

            float dw = sqrtf(pbr2) - sqrtf(tbr2);
            float dh = sqrtf(pbr3) - sqrtf(tbr3);
            float reg_wh = dw * dw + dh * dh;

            loss = contain + 5.0f * (reg_xy + reg_wh);
        }
    } else {
        int c = tid - CPB;
        const float* pc = &lds[c * 30];
        const float* tc = &lds[NF + c * 30];
        if (tc[4] > 0.0f) {
            float cls = 0.0f;
            #pragma unroll
            for (int e = 10; e < 30; ++e) {
                float d = pc[e] - tc[e];
                cls += d * d;
            }
            loss = cls;
        }
    }

    // ---- block reduction
    #pragma unroll
    for (int off = 32; off > 0; off >>= 1)
        loss += __shfl_down(loss, off, 64);

    int lane = tid & 63;
    int wid = tid >> 6;
    if (lane == 0) wsum[wid] = loss;
    __syncthreads();
    if (tid == 0)
        partial[bid] = wsum[0] + wsum[1] + wsum[2] + wsum[3];
}

__global__ __launch_bounds__(1024) void yolo_final(
    const float* __restrict__ partial,
    float* __restrict__ out)
{
    float s = 0.0f;
    for (int i = threadIdx.x; i < NBLOCKS; i += 1024)
        s += partial[i];

    #pragma unroll
    for (int off = 32; off > 0; off >>= 1)
        s += __shfl_down(s, off, 64);

    __shared__ float wsum[16];
    int lane = threadIdx.x & 63;
    int wid = threadIdx.x >> 6;
    if (lane == 0) wsum[wid] = s;
    __syncthreads();
    if (threadIdx.x == 0) {
        float tot = 0.0f;
        #pragma unroll
        for (int w = 0; w < 16; ++w) tot += wsum[w];
        out[0] = tot * (1.0f / 4096.0f);
    }
}

extern "C" void kernel_launch(void* const* d_in, const int* in_sizes, int n_in,
                              void* d_out, int out_size, void* d_ws, size_t ws_size,
                              hipStream_t stream) {
    const float* pred = (const float*)d_in[0];
    const float* targ = (const float*)d_in[1];
    float* out = (float*)d_out;
    float* partial = (float*)d_ws;

    yolo_partial<<<NBLOCKS, BLOCK, 0, stream>>>(pred, targ, partial);
    yolo_final<<<1, 1024, 0, stream>>>(partial, out);
}